// Round 2
// baseline (196.469 us; speedup 1.0000x reference)
//
#include <hip/hip_runtime.h>

#define LRC   0.01f
#define WCLIP 5.0f
#define LO   (-4.5951198501345898f)
#define HI   ( 4.5951198501345898f)

__device__ __forceinline__ unsigned short f2bf(float f) {
    unsigned int u = __float_as_uint(f);
    u += 0x7fffu + ((u >> 16) & 1u);          // RNE
    return (unsigned short)(u >> 16);
}
__device__ __forceinline__ float bflo(unsigned int p) { return __uint_as_float(p << 16); }
__device__ __forceinline__ float bfhi(unsigned int p) { return __uint_as_float(p & 0xffff0000u); }

// ---------------------------------------------------------------------------
// K1: distances GEMM (4096x512 @ 512x256) -> idx. 64x32 tile (N-split 8 for
//     occupancy: 512+64 blocks = ~2.25/CU vs 1.25 before), 4x2/thread, BK=64.
//     Per-output fmaf chain keeps identical (a,b,k) order -> idx bitwise
//     identical to the passing version. Blocks 512..575: transpose logits.
// ---------------------------------------------------------------------------
__global__ __launch_bounds__(256) void k1_idx_lt(
    const float* __restrict__ cmap,    // (4096, 512)
    const float* __restrict__ ctx,     // (512, 256)
    const float* __restrict__ cbias,   // (4096)
    const float* __restrict__ logits,  // (1024, 256)
    int*   __restrict__ idxb,          // (1024, 256)
    float* __restrict__ lT)            // (256, 1024)
{
    __shared__ __align__(16) float As[64 * 68];   // As[k][m], stride 68
    __shared__ __align__(16) float Bs[64 * 36];   // Bs[k][n], stride 36
    const int t   = threadIdx.x;
    const int blk = blockIdx.x;

    if (blk < 512) {
        const int gm = blk >> 3, gn = blk & 7;    // 64 m-tiles x 8 n-tiles
        const int m0 = gm << 6, n0 = gn << 5;
        const int tm = t >> 4, tn = t & 15;

        // A staging geometry (64k x 64m chunk, transposed store)
        const int rs = t >> 4;             // 0..15
        const int cs = (t & 15) << 2;      // 0..60
        // B staging geometry (64k x 32n chunk): 512 float4, 2/thread
        const int br = t >> 3;             // 0..31
        const int bc = (t & 7) << 2;       // 0..28

        float acc[4][2];
        #pragma unroll
        for (int i = 0; i < 4; i++) { acc[i][0] = 0.f; acc[i][1] = 0.f; }

        float4 va[4], vb[2];
        #pragma unroll
        for (int rep = 0; rep < 4; rep++)
            va[rep] = *(const float4*)(cmap + (m0 + (rep << 4) + rs) * 512 + cs);
        #pragma unroll
        for (int rep = 0; rep < 2; rep++)
            vb[rep] = *(const float4*)(ctx + ((rep << 5) + br) * 256 + n0 + bc);

        for (int k0 = 0; k0 < 512; k0 += 64) {
            __syncthreads();
            #pragma unroll
            for (int rep = 0; rep < 4; rep++) {
                const int r = (rep << 4) + rs;
                As[(cs + 0) * 68 + r] = va[rep].x;
                As[(cs + 1) * 68 + r] = va[rep].y;
                As[(cs + 2) * 68 + r] = va[rep].z;
                As[(cs + 3) * 68 + r] = va[rep].w;
            }
            #pragma unroll
            for (int rep = 0; rep < 2; rep++)
                *(float4*)(Bs + ((rep << 5) + br) * 36 + bc) = vb[rep];
            if (k0 + 64 < 512) {
                #pragma unroll
                for (int rep = 0; rep < 4; rep++)
                    va[rep] = *(const float4*)(cmap + (m0 + (rep << 4) + rs) * 512 + k0 + 64 + cs);
                #pragma unroll
                for (int rep = 0; rep < 2; rep++)
                    vb[rep] = *(const float4*)(ctx + (k0 + 64 + (rep << 5) + br) * 256 + n0 + bc);
            }
            __syncthreads();

            const float* ap = As + (tm << 2);
            const float* bp = Bs + (tn << 1);
            #pragma unroll 8
            for (int k = 0; k < 64; ++k) {
                float4 a4 = *(const float4*)(ap + k * 68);
                float2 b2 = *(const float2*)(bp + k * 36);
                acc[0][0] = fmaf(a4.x, b2.x, acc[0][0]);
                acc[0][1] = fmaf(a4.x, b2.y, acc[0][1]);
                acc[1][0] = fmaf(a4.y, b2.x, acc[1][0]);
                acc[1][1] = fmaf(a4.y, b2.y, acc[1][1]);
                acc[2][0] = fmaf(a4.z, b2.x, acc[2][0]);
                acc[2][1] = fmaf(a4.z, b2.y, acc[2][1]);
                acc[3][0] = fmaf(a4.w, b2.x, acc[3][0]);
                acc[3][1] = fmaf(a4.w, b2.y, acc[3][1]);
            }
        }
        // epilogue: thread's 4 m-rows = neuron s's 4 context maps, 2 n-cols
        const int s = (gm << 4) + tm;
        float cb[4];
        #pragma unroll
        for (int i = 0; i < 4; i++) cb[i] = cbias[(s << 2) + i];
        int2 iv;
        int* ivp = &iv.x;
        #pragma unroll
        for (int j = 0; j < 2; j++) {
            int v = 0;
            #pragma unroll
            for (int i = 0; i < 4; i++)
                v |= (acc[i][j] > cb[i]) ? (1 << i) : 0;
            ivp[j] = v;
        }
        *(int2*)(idxb + s * 256 + n0 + (tn << 1)) = iv;
    } else {
        // transpose one 64(i) x 64(b) tile of logits into lT
        float* T = As;
        const int bi = blk - 512;
        const int i0 = (bi >> 2) << 6;
        const int b0 = (bi & 3) << 6;
        #pragma unroll
        for (int rep = 0; rep < 4; rep++) {
            int flat4 = rep * 256 + t;
            int r = flat4 >> 4;
            int c = (flat4 & 15) << 2;
            float4 v = *(const float4*)(logits + (i0 + r) * 256 + b0 + c);
            T[(c + 0) * 68 + r] = v.x;
            T[(c + 1) * 68 + r] = v.y;
            T[(c + 2) * 68 + r] = v.z;
            T[(c + 3) * 68 + r] = v.w;
        }
        __syncthreads();
        #pragma unroll
        for (int rep = 0; rep < 4; rep++) {
            int flat4 = rep * 256 + t;
            int r = flat4 >> 4;
            int c = (flat4 & 15) << 2;
            *(float4*)(lT + (b0 + r) * 1024 + i0 + c) =
                *(const float4*)(T + r * 68 + c);
        }
    }
}

// ---------------------------------------------------------------------------
// K2: 512 blocks x 1024 thr, 2 neurons/block, single-pass bf16 LDS staging.
//   Dot restructured for issue-rate/latency (R1 was NOT BW-bound):
//   - thread = (o 0..7: i-range 128) x (bp 0..127: 2 adjacent b's)
//   - logits loads: coalesced dwordx2 (2 b's at once) -> 128 issues/thread
//     (was 256 scalar dwords), branchless next-quad register prefetch
//   - 4 independent FMA chains (2 g x 2 b) vs 2 before
//   - i-split 8 -> 2-stage tree reduction in 8 KB LDS (total 76.3 KB,
//     still 2 blocks/CU)
//   Epilogue reads weights back from LDS (bf16-exact for 1/1024 inputs),
//   writes outw directly -> no global weight re-read.
// ---------------------------------------------------------------------------
#define WSTRIDE 514   // dwords per LDS weight row (512 data + 2 pad)

__global__ __launch_bounds__(1024, 8) void k2_fwd_upd(
    const float* __restrict__ logits,   // (1024, 256)
    const float* __restrict__ targets,  // (256)
    const float* __restrict__ weights,  // (1024, 16, 1024)
    const float* __restrict__ bias,     // (1)
    const int*   __restrict__ idxb,     // (1024, 256)
    const float* __restrict__ lT,       // (256, 1024)
    float* __restrict__ outp,           // d_out first 1024*256
    float* __restrict__ outw)           // d_out + 1024*256
{
    __shared__ __align__(16) unsigned int wlds[32 * WSTRIDE];  // 65792 B bf16-packed
    __shared__ float red[4 * 2 * 256];                         // 8 KB tree buffer
    __shared__ float sig_lds[2 * 256];
    __shared__ int   lastb[32];
    __shared__ float cf_lds[32];

    const int t  = threadIdx.x;
    const int bp = t & 127;              // b-pair index: b = 2*bp, 2*bp+1
    const int b0 = bp << 1;
    const int o  = t >> 7;               // i-group 0..7 (128 i each)
    const int s0 = blockIdx.x << 1;      // 2 neurons/block

    if (t < 32) lastb[t] = -1;

    int jg[2][2], ro[2][2];
    #pragma unroll
    for (int g = 0; g < 2; g++) {
        int2 jv = *(const int2*)(idxb + (s0 + g) * 256 + b0);
        jg[g][0] = jv.x;  jg[g][1] = jv.y;
        ro[g][0] = ((g << 4) + jv.x) * WSTRIDE;
        ro[g][1] = ((g << 4) + jv.y) * WSTRIDE;
    }

    // ---- stage all 32 rows x 1024 cols as bf16 pairs (single pass) ----
    #pragma unroll
    for (int seg = 0; seg < 8; ++seg) {
        const int flat4 = (seg << 10) + t;
        const int r  = flat4 >> 8;              // 0..31 = g*16 + j
        const int c4 = (flat4 & 255) << 2;      // col 0..1020
        float4 v = *(const float4*)(weights +
                      ((size_t)(s0 + (r >> 4)) << 14) + ((r & 15) << 10) + c4);
        unsigned int p0 = (unsigned int)f2bf(v.x) | ((unsigned int)f2bf(v.y) << 16);
        unsigned int p1 = (unsigned int)f2bf(v.z) | ((unsigned int)f2bf(v.w) << 16);
        *(uint2*)(wlds + r * WSTRIDE + (c4 >> 1)) = make_uint2(p0, p1);
    }
    __syncthreads();

    // ---- dot: i-range [o*128, o*128+128), 2 b's, 4 indep chains ----
    const float2* lbase = (const float2*)logits + bp;   // logits[i][2bp..2bp+1]
    const int i0 = o << 7;

    float acc00 = 0.f, acc01 = 0.f, acc10 = 0.f, acc11 = 0.f;
    float2 c0 = lbase[(i0 + 0) * 128];
    float2 c1 = lbase[(i0 + 1) * 128];
    float2 c2 = lbase[(i0 + 2) * 128];
    float2 c3 = lbase[(i0 + 3) * 128];

    #pragma unroll 4
    for (int ii = 0; ii < 128; ii += 4) {
        const int ipn = (ii < 124) ? (i0 + ii + 4) : (i0 + 124);  // branchless tail
        float2 n0 = lbase[(ipn + 0) * 128];
        float2 n1 = lbase[(ipn + 1) * 128];
        float2 n2 = lbase[(ipn + 2) * 128];
        float2 n3 = lbase[(ipn + 3) * 128];

        const int ch = (i0 + ii) >> 1;          // dword offset in wlds row
        uint2 w00 = *(const uint2*)(wlds + ro[0][0] + ch);
        uint2 w01 = *(const uint2*)(wlds + ro[0][1] + ch);
        uint2 w10 = *(const uint2*)(wlds + ro[1][0] + ch);
        uint2 w11 = *(const uint2*)(wlds + ro[1][1] + ch);

        acc00 = fmaf(bflo(w00.x), c0.x, acc00);
        acc00 = fmaf(bfhi(w00.x), c1.x, acc00);
        acc00 = fmaf(bflo(w00.y), c2.x, acc00);
        acc00 = fmaf(bfhi(w00.y), c3.x, acc00);

        acc01 = fmaf(bflo(w01.x), c0.y, acc01);
        acc01 = fmaf(bfhi(w01.x), c1.y, acc01);
        acc01 = fmaf(bflo(w01.y), c2.y, acc01);
        acc01 = fmaf(bfhi(w01.y), c3.y, acc01);

        acc10 = fmaf(bflo(w10.x), c0.x, acc10);
        acc10 = fmaf(bfhi(w10.x), c1.x, acc10);
        acc10 = fmaf(bflo(w10.y), c2.x, acc10);
        acc10 = fmaf(bfhi(w10.y), c3.x, acc10);

        acc11 = fmaf(bflo(w11.x), c0.y, acc11);
        acc11 = fmaf(bfhi(w11.x), c1.y, acc11);
        acc11 = fmaf(bflo(w11.y), c2.y, acc11);
        acc11 = fmaf(bfhi(w11.y), c3.y, acc11);

        c0 = n0; c1 = n1; c2 = n2; c3 = n3;
    }

    // ---- 2-stage tree reduction over the 8 i-groups ----
    // phase 1: groups 4..7 -> slots 0..3; groups 0..3 absorb
    if (o >= 4) {
        *(float2*)(red + (((o - 4) << 1) + 0) * 256 + b0) = make_float2(acc00, acc01);
        *(float2*)(red + (((o - 4) << 1) + 1) * 256 + b0) = make_float2(acc10, acc11);
    }
    __syncthreads();
    if (o < 4) {
        float2 r0 = *(const float2*)(red + ((o << 1) + 0) * 256 + b0);
        float2 r1 = *(const float2*)(red + ((o << 1) + 1) * 256 + b0);
        acc00 += r0.x; acc01 += r0.y;
        acc10 += r1.x; acc11 += r1.y;
    }
    __syncthreads();
    // phase 2: groups 1..3 -> slots 0..2; group 0 finishes
    if (o >= 1 && o < 4) {
        *(float2*)(red + (((o - 1) << 1) + 0) * 256 + b0) = make_float2(acc00, acc01);
        *(float2*)(red + (((o - 1) << 1) + 1) * 256 + b0) = make_float2(acc10, acc11);
    }
    __syncthreads();
    if (o == 0) {
        #pragma unroll
        for (int g = 0; g < 2; g++) {
            float ax = (g == 0) ? acc00 : acc10;
            float ay = (g == 0) ? acc01 : acc11;
            float2 r0 = *(const float2*)(red + ((0 << 1) + g) * 256 + b0);
            float2 r1 = *(const float2*)(red + ((1 << 1) + g) * 256 + b0);
            float2 r2 = *(const float2*)(red + ((2 << 1) + g) * 256 + b0);
            float tx = ax + r0.x + r1.x + r2.x;
            float ty = ay + r0.y + r1.y + r2.y;
            float ox = fminf(fmaxf(tx, LO), HI);
            float oy = fminf(fmaxf(ty, LO), HI);
            if (s0 + g == 0) { ox = bias[0]; oy = bias[0]; }   // neuron 0
            *(float2*)(outp + (s0 + g) * 256 + b0) = make_float2(ox, oy);
            sig_lds[(g << 8) + b0 + 0] = 1.f / (1.f + __expf(-ox));
            sig_lds[(g << 8) + b0 + 1] = 1.f / (1.f + __expf(-oy));
            atomicMax(&lastb[(g << 4) + jg[g][0]], b0 + 0);
            atomicMax(&lastb[(g << 4) + jg[g][1]], b0 + 1);
        }
    }
    __syncthreads();
    if (t < 32) {
        int g  = t >> 4;
        int bb = lastb[t];
        float cfv = 0.f;
        if (bb >= 0) cfv = LRC * (sig_lds[(g << 8) + bb] - targets[bb]);
        cf_lds[t] = cfv;
    }
    __syncthreads();

    // ---- fused update epilogue: weights from LDS (bf16-exact), write-only ----
    const int er = t >> 5;               // row 0..31 = g*16 + j
    const int ec = (t & 31) << 2;        // col base 0..124
    const size_t rowbase = ((size_t)(s0 + (er >> 4)) << 14) + ((size_t)(er & 15) << 10);
    const int   col = lastb[er];         // uniform within 32-lane row group
    const float cf  = cf_lds[er];
    const float* lrow = lT + ((size_t)(col < 0 ? 0 : col) << 10);
    const unsigned int* wrow = wlds + er * WSTRIDE;
    #pragma unroll 4
    for (int seg = 0; seg < 8; ++seg) {
        const int c2 = ec + (seg << 7);
        uint2 wp = *(const uint2*)(wrow + (c2 >> 1));
        float4 res = make_float4(bflo(wp.x), bfhi(wp.x), bflo(wp.y), bfhi(wp.y));
        if (col >= 0) {
            float4 lv = *(const float4*)(lrow + c2);
            res.x = fminf(fmaxf(res.x - cf * lv.x, -WCLIP), WCLIP);
            res.y = fminf(fmaxf(res.y - cf * lv.y, -WCLIP), WCLIP);
            res.z = fminf(fmaxf(res.z - cf * lv.z, -WCLIP), WCLIP);
            res.w = fminf(fmaxf(res.w - cf * lv.w, -WCLIP), WCLIP);
        }
        *(float4*)(outw + rowbase + c2) = res;
    }
}

// ---------------------------------------------------------------------------
extern "C" void kernel_launch(void* const* d_in, const int* in_sizes, int n_in,
                              void* d_out, int out_size, void* d_ws, size_t ws_size,
                              hipStream_t stream) {
    const float* logits  = (const float*)d_in[0];   // (1024, 256)
    const float* ctx     = (const float*)d_in[1];   // (512, 256)
    const float* targets = (const float*)d_in[2];   // (256)
    const float* weights = (const float*)d_in[3];   // (1024, 16, 1024)
    const float* cmap    = (const float*)d_in[4];   // (1024, 4, 512)
    const float* cbias   = (const float*)d_in[5];   // (1024, 4, 1)
    const float* bias    = (const float*)d_in[6];   // (1)

    float* outp = (float*)d_out;                    // (1024, 256)
    float* outw = outp + 1024 * 256;                // (1024, 16, 1024)

    char* ws = (char*)d_ws;
    int*   idxb = (int*)ws;                         // 1 MB
    float* lT   = (float*)(ws + (1 << 20));         // 1 MB

    k1_idx_lt <<<576, 256, 0, stream>>>(cmap, ctx, cbias, logits, idxb, lT);
    k2_fwd_upd<<<512, 1024, 0, stream>>>(logits, targets, weights, bias, idxb,
                                         lT, outp, outw);
}